// Round 2
// baseline (332.697 us; speedup 1.0000x reference)
//
#include <hip/hip_runtime.h>

#define H 1024
#define W 1024
#define K 11
#define RAD 5
#define ROWS 64              /* output rows per block strip (32 regressed: occupancy is residency- */
                             /* capped ~11-16 waves/CU regardless of grid; 64 minimizes h-redundancy) */
#define NIN (ROWS + K - 1)   /* 74 input rows per strip */
#define RING 12              /* ring of 12 (not 11) so slot=i%12 AND parity=i&1 are both static */
#define BW 256               /* columns per block (1 col/thread) */

typedef float v2f __attribute__((ext_vector_type(2)));

__global__ void zero_out_kernel(float* out) {
    if (threadIdx.x == 0) out[0] = 0.0f;
}

__device__ __forceinline__ float4 ld4u(const float* p) {
    float4 v;
    __builtin_memcpy(&v, p, sizeof(float4));
    return v;
}

__device__ __forceinline__ v2f pkfma(v2f a, v2f b, v2f c) {
    return __builtin_elementwise_fma(a, b, c);
}

template<bool FAST>
__device__ __forceinline__ void load_row(const float* __restrict__ r1,
                                         const float* __restrict__ r2,
                                         int col, float* x, float* y) {
    if (FAST) {
        const float* a1 = r1 + (col - RAD);
        const float* a2 = r2 + (col - RAD);
        float4 v0 = ld4u(a1), v1 = ld4u(a1 + 4), v2 = ld4u(a1 + 8);
        float4 u0 = ld4u(a2), u1 = ld4u(a2 + 4), u2 = ld4u(a2 + 8);
        x[0]=v0.x; x[1]=v0.y; x[2]=v0.z; x[3]=v0.w;
        x[4]=v1.x; x[5]=v1.y; x[6]=v1.z; x[7]=v1.w;
        x[8]=v2.x; x[9]=v2.y; x[10]=v2.z; x[11]=v2.w;
        y[0]=u0.x; y[1]=u0.y; y[2]=u0.z; y[3]=u0.w;
        y[4]=u1.x; y[5]=u1.y; y[6]=u1.z; y[7]=u1.w;
        y[8]=u2.x; y[9]=u2.y; y[10]=u2.z; y[11]=u2.w;
    } else {
        #pragma unroll
        for (int m = 0; m < 12; ++m) {
            const int gc = col - RAD + m;
            const bool ok = (unsigned)gc < (unsigned)W;
            x[m] = ok ? r1[gc] : 0.0f;
            y[m] = ok ? r2[gc] : 0.0f;
        }
    }
}

template<bool FAST>
__device__ __forceinline__ float run_strip(const float* __restrict__ p1,
                                           const float* __restrict__ p2,
                                           int col, int rin0, const float* gw) {
    // Rings sized 12: slot for row i is i%12 (static = p), parity i&1 static too.
    // Vertical taps j=0..10 for output row i read slots (p+2+j)%12 — the 11 live
    // slots; (p+1)%12 holds the dead row i-11.
    v2f  rmu[RING], rsq[RING];
    float rxy[RING];
    // Double-buffered register row-windows: loads for row i+1 issue BEFORE the
    // dependent compute of row i, giving each load one full row-step (~160 cyc
    // per wave, x waves/SIMD) to land. This is the ILP latency fix; TLP is
    // residency-capped (R1: doubling grid left occupancy at 34%).
    float xb[2][12], yb[2][12];
    float acc = 0.0f;
    const float C1 = 1e-4f;
    const float C2 = 9e-4f;

    {   // prologue: first strip row into parity 0
        const int rr0 = min(max(rin0, 0), H - 1);
        load_row<FAST>(p1 + (size_t)rr0 * W, p2 + (size_t)rr0 * W, col, xb[0], yb[0]);
    }

    #pragma unroll 1
    for (int base = 0; base < NIN; base += RING) {
        #pragma unroll
        for (int p = 0; p < RING; ++p) {
            const int i = base + p;
            if (i < NIN) {
                // ---- prefetch row i+1 into the other parity (issue-early) ----
                {
                    const int rn  = rin0 + i + 1;
                    const int rrn = min(max(rn, 0), H - 1);
                    load_row<FAST>(p1 + (size_t)rrn * W, p2 + (size_t)rrn * W, col,
                                   xb[(p + 1) & 1], yb[(p + 1) & 1]);
                }

                const int r = rin0 + i;                        // block-uniform
                const float s = ((unsigned)r < (unsigned)H) ? 1.0f : 0.0f;
                const float* x = xb[p & 1];
                const float* y = yb[p & 1];

                // ---- Horizontal 11-tap, tap-paired packed fp32 ----
                v2f amx = {0.f,0.f}, amy = {0.f,0.f};
                v2f axx = {0.f,0.f}, ayy = {0.f,0.f}, axy = {0.f,0.f};
                #pragma unroll
                for (int e = 0; e < 5; ++e) {
                    v2f w2 = { gw[2*e], gw[2*e+1] };
                    v2f xp = { x[2*e], x[2*e+1] };
                    v2f yp = { y[2*e], y[2*e+1] };
                    v2f wxp = w2 * xp;
                    v2f wyp = w2 * yp;
                    amx += wxp;
                    amy += wyp;
                    axx = pkfma(wxp, xp, axx);
                    ayy = pkfma(wyp, yp, ayy);
                    axy = pkfma(wxp, yp, axy);
                }
                const float twx = gw[10] * x[10];
                const float twy = gw[10] * y[10];
                const float hmx = (amx.x + amx.y) + twx;
                const float hmy = (amy.x + amy.y) + twy;
                const float hxx = fmaf(twx, x[10], axx.x + axx.y);
                const float hyy = fmaf(twy, y[10], ayy.x + ayy.y);
                const float hxy = fmaf(twx, y[10], axy.x + axy.y);

                v2f s2 = { s, s };
                rmu[p] = s2 * (v2f){ hmx, hmy };
                rsq[p] = s2 * (v2f){ hxx, hyy };
                rxy[p] = s * hxy;

                // ---- Vertical 11-tap, plane-paired packed + SSIM ----
                if (i >= K - 1) {
                    v2f mu = {0.f,0.f}, sq = {0.f,0.f};
                    float xy = 0.f;
                    #pragma unroll
                    for (int j = 0; j < K; ++j) {
                        const int sl = (p + 2 + j) % RING;     // static after unroll
                        const float w = gw[j];
                        v2f w2 = { w, w };
                        mu = pkfma(w2, rmu[sl], mu);
                        sq = pkfma(w2, rsq[sl], sq);
                        xy = fmaf(w, rxy[sl], xy);
                    }
                    v2f m2 = mu * mu;                          // {mx2, my2}
                    const float mxy  = mu.x * mu.y;
                    v2f sg = sq - m2;                          // {sx2, sy2}
                    const float sxyv = xy - mxy;
                    const float num = fmaf(2.0f, mxy,  C1) * fmaf(2.0f, sxyv, C2);
                    const float den = (m2.x + m2.y + C1) * (sg.x + sg.y + C2);
                    acc += num * __builtin_amdgcn_rcpf(den);
                }
            }
        }
    }
    return acc;
}

__launch_bounds__(256, 4)
__global__ void ssim_kernel(const float* __restrict__ img1,
                            const float* __restrict__ img2,
                            const float* __restrict__ kern,
                            float* __restrict__ out,
                            float inv_n) {
    __shared__ float wsum[4];

    const int tid = threadIdx.x;
    const int col = blockIdx.x * BW + tid;
    const int ry0 = blockIdx.y * ROWS;
    const int b   = blockIdx.z;

    // 1D gaussian = row sums of normalized 2D kernel (exact). Pin to SGPRs.
    float gw[K];
    #pragma unroll
    for (int t = 0; t < K; ++t) {
        float s = 0.0f;
        #pragma unroll
        for (int j = 0; j < K; ++j) s += kern[t * K + j];
        gw[t] = __int_as_float(__builtin_amdgcn_readfirstlane(__float_as_int(s)));
    }

    const float* __restrict__ p1 = img1 + (size_t)b * H * W;
    const float* __restrict__ p2 = img2 + (size_t)b * H * W;
    const int rin0 = ry0 - RAD;

    // Wave-uniform fast/slow split: fast iff ALL lanes' 12-col windows in-bounds.
    const bool colfast = (col >= RAD) && (col + RAD + 1 < W);
    const unsigned long long bal = __ballot(colfast);
    float acc;
    if (bal == ~0ULL) {
        acc = run_strip<true>(p1, p2, col, rin0, gw);
    } else {
        acc = run_strip<false>(p1, p2, col, rin0, gw);
    }

    // Wave butterfly reduce -> cross-wave via LDS -> one atomic per block.
    for (int off = 32; off > 0; off >>= 1)
        acc += __shfl_down(acc, off, 64);
    if ((tid & 63) == 0) wsum[tid >> 6] = acc;
    __syncthreads();
    if (tid == 0) {
        const float s = wsum[0] + wsum[1] + wsum[2] + wsum[3];
        atomicAdd(out, s * inv_n);
    }
}

extern "C" void kernel_launch(void* const* d_in, const int* in_sizes, int n_in,
                              void* d_out, int out_size, void* d_ws, size_t ws_size,
                              hipStream_t stream) {
    const float* img1 = (const float*)d_in[0];
    const float* img2 = (const float*)d_in[1];
    const float* kern = (const float*)d_in[2];
    float* out = (float*)d_out;

    const int B = in_sizes[0] / (H * W);
    const float inv_n = 1.0f / ((float)B * (float)H * (float)W);

    zero_out_kernel<<<dim3(1), dim3(64), 0, stream>>>(out);

    dim3 grid(W / BW, H / ROWS, B);
    ssim_kernel<<<grid, dim3(256), 0, stream>>>(img1, img2, kern, out, inv_n);
}

// Round 4
// 232.267 us; speedup vs baseline: 1.4324x; 1.4324x over previous
//
#include <hip/hip_runtime.h>

#define H 1024
#define W 1024
#define K 11
#define RAD 5
#define ROWS 32              /* output rows per strip; 32 keeps wave supply at 4/SIMD now that  */
                             /* grid.x halved (2 cols/thread). Redundancy 42/32 = 1.31          */
#define NIN (ROWS + K - 1)   /* 42 input rows per strip */
#define TPB 256
#define CPT 2                /* output columns per thread: the L1-traffic lever. The 12-float   */
                             /* window serves BOTH cols -> L1 bytes/output halves               */
#define BWC (TPB * CPT)      /* 512 output cols per block */

typedef float v2f __attribute__((ext_vector_type(2)));

__global__ void zero_out_kernel(float* out) {
    if (threadIdx.x == 0) out[0] = 0.0f;
}

__device__ __forceinline__ float4 ld4u(const float* p) {
    float4 v;
    __builtin_memcpy(&v, p, sizeof(float4));
    return v;
}

__device__ __forceinline__ v2f pkfma(v2f a, v2f b, v2f c) {
    return __builtin_elementwise_fma(a, b, c);
}

// Load the 12-float window [c0-5, c0+7) for the column pair {c0, c0+1}.
template<bool FAST>
__device__ __forceinline__ void load_row(const float* __restrict__ r1,
                                         const float* __restrict__ r2,
                                         int c0, float* x, float* y) {
    if (FAST) {
        const float* a1 = r1 + (c0 - RAD);
        const float* a2 = r2 + (c0 - RAD);
        float4 v0 = ld4u(a1), v1 = ld4u(a1 + 4), v2 = ld4u(a1 + 8);
        float4 u0 = ld4u(a2), u1 = ld4u(a2 + 4), u2 = ld4u(a2 + 8);
        x[0]=v0.x; x[1]=v0.y; x[2]=v0.z; x[3]=v0.w;
        x[4]=v1.x; x[5]=v1.y; x[6]=v1.z; x[7]=v1.w;
        x[8]=v2.x; x[9]=v2.y; x[10]=v2.z; x[11]=v2.w;
        y[0]=u0.x; y[1]=u0.y; y[2]=u0.z; y[3]=u0.w;
        y[4]=u1.x; y[5]=u1.y; y[6]=u1.z; y[7]=u1.w;
        y[8]=u2.x; y[9]=u2.y; y[10]=u2.z; y[11]=u2.w;
    } else {
        #pragma unroll
        for (int m = 0; m < 12; ++m) {
            const int gc = c0 - RAD + m;
            const bool ok = (unsigned)gc < (unsigned)W;
            x[m] = ok ? r1[gc] : 0.0f;
            y[m] = ok ? r2[gc] : 0.0f;
        }
    }
}

template<bool FAST>
__device__ __forceinline__ float run_strip(const float* __restrict__ p1,
                                           const float* __restrict__ p2,
                                           int c0, int rin0, const float* gw) {
    // Rings of horizontal conv results, v2f-packed ACROSS THE COLUMN PAIR.
    // 5 fields x 11 rows x 2 cols = 110 floats, all statically indexed
    // (outer loop fully unrolls -> straight-line SSA, no scratch; R2 lesson).
    v2f rmx[K], rmy[K], rxx[K], ryy[K], rxy[K];
    v2f acc2 = {0.f, 0.f};
    const v2f C1v = {1e-4f, 1e-4f};
    const v2f C2v = {9e-4f, 9e-4f};
    const v2f two = {2.0f, 2.0f};

    for (int base = 0; base < NIN; base += K) {
        #pragma unroll
        for (int p = 0; p < K; ++p) {
            const int i = base + p;
            if (i < NIN) {
                const int r  = rin0 + i;                       // block-uniform
                const int rr = min(max(r, 0), H - 1);          // clamped (valid addr)
                const float s = ((unsigned)r < (unsigned)H) ? 1.0f : 0.0f;

                float x[12], y[12];
                load_row<FAST>(p1 + (size_t)rr * W, p2 + (size_t)rr * W, c0, x, y);

                // ---- Horizontal 11-tap, column-pair packed fp32 ----
                // col0 window = x[j], col1 window = x[j+1]
                v2f hmx = {0.f,0.f}, hmy = {0.f,0.f};
                v2f hxx = {0.f,0.f}, hyy = {0.f,0.f}, hxy = {0.f,0.f};
                #pragma unroll
                for (int j = 0; j < K; ++j) {
                    const v2f w2 = { gw[j], gw[j] };
                    const v2f xp = { x[j], x[j+1] };
                    const v2f yp = { y[j], y[j+1] };
                    const v2f wx = w2 * xp;
                    const v2f wy = w2 * yp;
                    hmx += wx;
                    hmy += wy;
                    hxx = pkfma(wx, xp, hxx);
                    hyy = pkfma(wy, yp, hyy);
                    hxy = pkfma(wx, yp, hxy);
                }
                const v2f s2 = { s, s };
                rmx[p] = s2 * hmx;
                rmy[p] = s2 * hmy;
                rxx[p] = s2 * hxx;
                ryy[p] = s2 * hyy;
                rxy[p] = s2 * hxy;

                // ---- Vertical 11-tap + SSIM, column-pair packed ----
                if (i >= K - 1) {
                    v2f mx = {0.f,0.f}, my = {0.f,0.f};
                    v2f vxx = {0.f,0.f}, vyy = {0.f,0.f}, vxy = {0.f,0.f};
                    #pragma unroll
                    for (int j = 0; j < K; ++j) {
                        const int sl = (p + 1 + j) % K;        // static after unroll
                        const v2f w2 = { gw[j], gw[j] };
                        mx  = pkfma(w2, rmx[sl], mx);
                        my  = pkfma(w2, rmy[sl], my);
                        vxx = pkfma(w2, rxx[sl], vxx);
                        vyy = pkfma(w2, ryy[sl], vyy);
                        vxy = pkfma(w2, rxy[sl], vxy);
                    }
                    const v2f m2x = mx * mx;
                    const v2f m2y = my * my;
                    const v2f mxy = mx * my;
                    const v2f sgx = vxx - m2x;
                    const v2f sgy = vyy - m2y;
                    const v2f sxy = vxy - mxy;
                    const v2f num = pkfma(two, mxy, C1v) * pkfma(two, sxy, C2v);
                    const v2f den = (m2x + m2y + C1v) * (sgx + sgy + C2v);
                    const v2f rd  = { __builtin_amdgcn_rcpf(den.x),
                                      __builtin_amdgcn_rcpf(den.y) };
                    acc2 = pkfma(num, rd, acc2);
                }
            }
        }
    }
    return acc2.x + acc2.y;
}

__launch_bounds__(256, 2)
__global__ void ssim_kernel(const float* __restrict__ img1,
                            const float* __restrict__ img2,
                            const float* __restrict__ kern,
                            float* __restrict__ out,
                            float inv_n) {
    __shared__ float wsum[4];

    const int tid = threadIdx.x;
    const int c0  = blockIdx.x * BWC + tid * CPT;
    const int ry0 = blockIdx.y * ROWS;
    const int b   = blockIdx.z;

    // 1D gaussian = row sums of normalized 2D kernel (exact). Pin to SGPRs.
    float gw[K];
    #pragma unroll
    for (int t = 0; t < K; ++t) {
        float s = 0.0f;
        #pragma unroll
        for (int j = 0; j < K; ++j) s += kern[t * K + j];
        gw[t] = __int_as_float(__builtin_amdgcn_readfirstlane(__float_as_int(s)));
    }

    const float* __restrict__ p1 = img1 + (size_t)b * H * W;
    const float* __restrict__ p2 = img2 + (size_t)b * H * W;
    const int rin0 = ry0 - RAD;

    // Wave-uniform fast/slow split: fast iff ALL 12 window floats in-bounds.
    const bool colfast = (c0 >= RAD) && (c0 - RAD + 12 <= W);
    const unsigned long long bal = __ballot(colfast);
    float acc;
    if (bal == ~0ULL) {
        acc = run_strip<true>(p1, p2, c0, rin0, gw);
    } else {
        acc = run_strip<false>(p1, p2, c0, rin0, gw);
    }

    // Wave butterfly reduce -> cross-wave via LDS -> one atomic per block.
    for (int off = 32; off > 0; off >>= 1)
        acc += __shfl_down(acc, off, 64);
    if ((tid & 63) == 0) wsum[tid >> 6] = acc;
    __syncthreads();
    if (tid == 0) {
        const float s = wsum[0] + wsum[1] + wsum[2] + wsum[3];
        atomicAdd(out, s * inv_n);
    }
}

extern "C" void kernel_launch(void* const* d_in, const int* in_sizes, int n_in,
                              void* d_out, int out_size, void* d_ws, size_t ws_size,
                              hipStream_t stream) {
    const float* img1 = (const float*)d_in[0];
    const float* img2 = (const float*)d_in[1];
    const float* kern = (const float*)d_in[2];
    float* out = (float*)d_out;

    const int B = in_sizes[0] / (H * W);
    const float inv_n = 1.0f / ((float)B * (float)H * (float)W);

    zero_out_kernel<<<dim3(1), dim3(64), 0, stream>>>(out);

    dim3 grid(W / BWC, H / ROWS, B);
    ssim_kernel<<<grid, dim3(256), 0, stream>>>(img1, img2, kern, out, inv_n);
}